// Round 6
// baseline (565.390 us; speedup 1.0000x reference)
//
#include <hip/hip_runtime.h>

// Problem shape (hardcoded from reference setup_inputs):
// B=4, N=1024, C=2048, H=2*C=4096, num_head=32, d_head=64
#define C_DIM   2048
#define H_DIM   4096
#define NSEQ    1024
#define NBATCH  4
#define BN_ROWS 4096    // B*N
#define NHEAD   32
#define DHEAD   64

typedef __attribute__((ext_vector_type(8))) short  short8;
typedef __attribute__((ext_vector_type(4))) float  f32x4;

__device__ __forceinline__ float bf2f(unsigned short u) {
    union { unsigned int i; float f; } v; v.i = ((unsigned int)u) << 16; return v.f;
}
__device__ __forceinline__ unsigned short f2bf(float f) {
    union { float f; unsigned int i; } v; v.f = f;
    unsigned int r = v.i + 0x7fffu + ((v.i >> 16) & 1u);   // round-to-nearest-even
    return (unsigned short)(r >> 16);
}

// async global->LDS, 16B per lane; lds base must be wave-uniform, lane i
// lands at lds + i*16 (measured m97/m104 semantics).
#define G2L16(gp, lp) \
    __builtin_amdgcn_global_load_lds((const __attribute__((address_space(1))) void*)(gp), \
                                     (__attribute__((address_space(3))) void*)(lp), 16, 0, 0)

// ---------------------------------------------------------------------------
// Fused fp32 -> bf16 conversion, 16 elems/thread (4096/block). Boundaries:
//   x:2048 | wq:1024 | wk:1024 | wv:1024 | fc1w:2048 | fc2w:2048 (tot 9216)
// ---------------------------------------------------------------------------
__global__ __launch_bounds__(256)
void cvt_all(const float* __restrict__ x,   unsigned short* __restrict__ xo,
             const float* __restrict__ w0,  unsigned short* __restrict__ w0o,
             const float* __restrict__ w1,  unsigned short* __restrict__ w1o,
             const float* __restrict__ w2,  unsigned short* __restrict__ w2o,
             const float* __restrict__ w3,  unsigned short* __restrict__ w3o,
             const float* __restrict__ w4,  unsigned short* __restrict__ w4o)
{
    int bid = blockIdx.x;
    const float* src; unsigned short* dst;
    if      (bid < 2048) { src = x;  dst = xo;  }
    else if (bid < 3072) { src = w0; dst = w0o; bid -= 2048; }
    else if (bid < 4096) { src = w1; dst = w1o; bid -= 3072; }
    else if (bid < 5120) { src = w2; dst = w2o; bid -= 4096; }
    else if (bid < 7168) { src = w3; dst = w3o; bid -= 5120; }
    else                 { src = w4; dst = w4o; bid -= 7168; }
    const size_t i = ((size_t)bid * 256 + threadIdx.x) * 16;
    #pragma unroll
    for (int h = 0; h < 2; ++h) {
        float4 a = *(const float4*)(src + i + h * 8);
        float4 b = *(const float4*)(src + i + h * 8 + 4);
        unsigned short o[8] = { f2bf(a.x), f2bf(a.y), f2bf(a.z), f2bf(a.w),
                                f2bf(b.x), f2bf(b.y), f2bf(b.z), f2bf(b.w) };
        *(int4*)(dst + i + h * 8) = *(const int4*)o;
    }
}

// ---------------------------------------------------------------------------
// Fused QKV GEMM — m97 2-barrier structure (verified 124.4 us, VGPR 76).
// NEW this round: XCD-aware m-major block swizzle (T1). grid (32,48);
// hwid = bx + by*32 is the HW dispatch id (round-robins XCDs); remap so
// each XCD owns a contiguous m-major chunk of 192 tiles = 4 m-blocks ->
// A-slice 2 MB = L2-resident; B streams from L3 (written by cvt, shared).
// Mechanism: the vmcnt(0)-before-barrier drain waits on the SLOWEST of 32
// in-flight G2L16s; killing A's L3/HBM misses cuts the tail.
// ---------------------------------------------------------------------------
__global__ __launch_bounds__(256)
void gemm_qkv(const unsigned short* __restrict__ A,
              const unsigned short* __restrict__ Wq,
              const unsigned short* __restrict__ Wk,
              const unsigned short* __restrict__ Wv,
              unsigned short* __restrict__ Qo,
              unsigned short* __restrict__ Ko,
              unsigned short* __restrict__ Vo)
{
    __shared__ unsigned short As[128 * 32];
    __shared__ unsigned short Bs[128 * 32];

    const int t    = threadIdx.x;
    const int lane = t & 63;
    const int wave = t >> 6;

    // XCD swizzle: bijective since nwg=1536 % 8 == 0
    const int hwid = blockIdx.x + blockIdx.y * 32;
    const int swz  = (hwid & 7) * 192 + (hwid >> 3);
    const int m0   = (swz / 48) * 128;
    const int ng   = (swz % 48) * 128;         // global n in [0,6144)

    const unsigned short* B; unsigned short* Cp; int n0;
    if      (ng < 2048) { B = Wq; Cp = Qo; n0 = ng; }
    else if (ng < 4096) { B = Wk; Cp = Ko; n0 = ng - 2048; }
    else                { B = Wv; Cp = Vo; n0 = ng - 4096; }

    const int wm = (wave >> 1) * 64, wn = (wave & 1) * 64;
    const int lr = lane & 15;
    const int kq = lane >> 4;

    f32x4 acc[4][4] = {};

    const int lrow = lane >> 2;
    const int lcol = (lane & 3) * 8;

    for (int kt = 0; kt < C_DIM; kt += 32) {
        __syncthreads();
        #pragma unroll
        for (int p = 0; p < 2; ++p) {
            const int rb = wave * 32 + p * 16;
            G2L16(&A[(size_t)(m0 + rb + lrow) * C_DIM + kt + lcol], &As[rb * 32]);
            G2L16(&B[(size_t)(n0 + rb + lrow) * C_DIM + kt + lcol], &Bs[rb * 32]);
        }
        __syncthreads();

        short8 af[4], bf[4];
        #pragma unroll
        for (int i = 0; i < 4; ++i)
            af[i] = *(const short8*)&As[(wm + i * 16 + lr) * 32 + kq * 8];
        #pragma unroll
        for (int j = 0; j < 4; ++j)
            bf[j] = *(const short8*)&Bs[(wn + j * 16 + lr) * 32 + kq * 8];
        #pragma unroll
        for (int i = 0; i < 4; ++i)
            #pragma unroll
            for (int j = 0; j < 4; ++j)
                acc[i][j] = __builtin_amdgcn_mfma_f32_16x16x32_bf16(af[i], bf[j], acc[i][j], 0, 0, 0);
    }

    #pragma unroll
    for (int j = 0; j < 4; ++j) {
        const int col = n0 + wn + j * 16 + lr;
        #pragma unroll
        for (int i = 0; i < 4; ++i) {
            #pragma unroll
            for (int r = 0; r < 4; ++r) {
                const int row = m0 + wm + i * 16 + kq * 4 + r;
                Cp[(size_t)row * C_DIM + col] = f2bf(acc[i][j][r]);
            }
        }
    }
}

// ---------------------------------------------------------------------------
// 256x256 8-phase GEMM (verified R3/R4; 0 bank conflicts) — fc1.
// ---------------------------------------------------------------------------
template<int EPI>
__device__ __forceinline__
void gemm256_body(const unsigned short* __restrict__ A,
                  const unsigned short* __restrict__ B,
                  const float* __restrict__ bias,
                  unsigned short* __restrict__ C,
                  const int m0, const int n0, const int K, const int ldc)
{
    __shared__ unsigned short As[2][256 * 64];
    __shared__ unsigned short Bs[2][256 * 64];

    const int t  = threadIdx.x;
    const int l  = t & 63;
    const int w  = t >> 6;          // 0..7
    const int wr = w >> 2;          // 0..1  (M half)
    const int wc = w & 3;           // 0..3  (N quarter)
    const int lr = l & 15;
    const int kq = l >> 4;
    const int slotA = lr & 7;       // read-side swizzle term

    const int sr = l >> 3;                    // row 0..7 within 8-row group
    const int sg = ((l & 7) ^ sr) * 8;        // swizzled source granule (ushort)

    f32x4 acc[8][4] = {};
    short8 bf[4][2], af[2][2];

#define STG(src, srow0, ktile, ldsdst) do {                                         \
    const unsigned short* gp0_ = (src) + (size_t)((srow0) + w * 8 + sr) * K         \
                                  + (ktile) * 64 + sg;                              \
    const unsigned short* gp1_ = (src) + (size_t)((srow0) + 64 + w * 8 + sr) * K    \
                                  + (ktile) * 64 + sg;                              \
    G2L16(gp0_, (ldsdst) + (w * 8) * 64);                                           \
    G2L16(gp1_, (ldsdst) + (64 + w * 8) * 64);                                      \
  } while (0)

#define LDB(buf) do {                                                               \
    _Pragma("unroll") for (int n_ = 0; n_ < 4; ++n_)                                \
      _Pragma("unroll") for (int ks_ = 0; ks_ < 2; ++ks_)                           \
        bf[n_][ks_] = *(const short8*)&Bs[buf][                                     \
            (wc * 64 + n_ * 16 + lr) * 64 + (((ks_ << 2) | kq) ^ slotA) * 8];       \
  } while (0)

#define LDA(buf, q) do {                                                            \
    _Pragma("unroll") for (int i_ = 0; i_ < 2; ++i_)                                \
      _Pragma("unroll") for (int ks_ = 0; ks_ < 2; ++ks_)                           \
        af[i_][ks_] = *(const short8*)&As[buf][                                     \
            (wr * 128 + ((q) * 2 + i_) * 16 + lr) * 64                              \
            + (((ks_ << 2) | kq) ^ slotA) * 8];                                     \
  } while (0)

#define MM(q) do {                                                                  \
    __builtin_amdgcn_s_setprio(1);                                                  \
    _Pragma("unroll") for (int i_ = 0; i_ < 2; ++i_)                                \
      _Pragma("unroll") for (int n_ = 0; n_ < 4; ++n_)                              \
        _Pragma("unroll") for (int ks_ = 0; ks_ < 2; ++ks_)                         \
          acc[(q) * 2 + i_][n_] = __builtin_amdgcn_mfma_f32_16x16x32_bf16(          \
              af[i_][ks_], bf[n_][ks_], acc[(q) * 2 + i_][n_], 0, 0, 0);            \
    __builtin_amdgcn_s_setprio(0);                                                  \
  } while (0)

#define BARR() __builtin_amdgcn_s_barrier()
#define WLG0() asm volatile("s_waitcnt lgkmcnt(0)" ::: "memory")

    const int NT = K >> 6;      // K-tiles of 64
    const int IT = NT >> 1;     // iterations (2 tiles each)

    STG(B, n0,       0, &Bs[0][0]);
    STG(B, n0 + 128, 0, &Bs[0][128 * 64]);
    STG(A, m0,       0, &As[0][0]);
    STG(A, m0 + 128, 0, &As[0][128 * 64]);
    STG(B, n0,       1, &Bs[1][0]);
    STG(B, n0 + 128, 1, &Bs[1][128 * 64]);
    asm volatile("s_waitcnt vmcnt(4)" ::: "memory");   // T0 landed; T1.B in flight
    BARR();

    for (int it = 0; it < IT; ++it) {
        const int T1 = 2 * it + 1, T2 = 2 * it + 2, T3 = 2 * it + 3;
        const bool haveT2 = (T2 < NT), haveT3 = (T3 < NT);

        LDB(0); LDA(0, 0);
        STG(A, m0, T1, &As[1][0]);
        BARR(); WLG0(); MM(0); BARR();

        LDA(0, 1);
        STG(A, m0 + 128, T1, &As[1][128 * 64]);
        BARR(); WLG0(); MM(1); BARR();

        LDA(0, 2);
        if (haveT2) STG(B, n0, T2, &Bs[0][0]);
        BARR(); WLG0(); MM(2); BARR();

        LDA(0, 3);
        if (haveT2) STG(B, n0 + 128, T2, &Bs[0][128 * 64]);
        BARR(); WLG0(); MM(3);
        if (haveT2) asm volatile("s_waitcnt vmcnt(4)" ::: "memory");
        else        asm volatile("s_waitcnt vmcnt(0)" ::: "memory");
        BARR();

        LDB(1); LDA(1, 0);
        if (haveT2) STG(A, m0, T2, &As[0][0]);
        BARR(); WLG0(); MM(0); BARR();

        LDA(1, 1);
        if (haveT2) STG(A, m0 + 128, T2, &As[0][128 * 64]);
        BARR(); WLG0(); MM(1); BARR();

        LDA(1, 2);
        if (haveT3) STG(B, n0, T3, &Bs[1][0]);
        BARR(); WLG0(); MM(2); BARR();

        LDA(1, 3);
        if (haveT3) STG(B, n0 + 128, T3, &Bs[1][128 * 64]);
        BARR(); WLG0(); MM(3);
        if (it + 1 < IT) asm volatile("s_waitcnt vmcnt(4)" ::: "memory");
        BARR();
    }

    #pragma unroll
    for (int n = 0; n < 4; ++n) {
        const int col = n0 + wc * 64 + n * 16 + lr;
        float bv = 0.f;
        if (EPI > 0) bv = bias[col];
        #pragma unroll
        for (int m = 0; m < 8; ++m) {
            #pragma unroll
            for (int r = 0; r < 4; ++r) {
                const int row = m0 + wr * 128 + m * 16 + kq * 4 + r;
                float v = acc[m][n][r] + bv;
                if (EPI == 1) v = fmaxf(v, 0.f);
                C[(size_t)row * ldc + col] = f2bf(v);
            }
        }
    }
#undef STG
#undef LDB
#undef LDA
#undef MM
#undef BARR
#undef WLG0
}

__global__ __launch_bounds__(512, 2)
void gemm256_fc1(const unsigned short* __restrict__ A,
                 const unsigned short* __restrict__ B,
                 const float* __restrict__ bias,
                 unsigned short* __restrict__ C)
{
    // XCD swizzle: grid (16,16)=256, chunk 32/XCD = 2 m-blocks (512 rows,
    // A-slice 2 MB -> L2-resident); m-major decode.
    const int hwid = blockIdx.x + blockIdx.y * 16;
    const int swz  = (hwid & 7) * 32 + (hwid >> 3);
    gemm256_body<1>(A, B, bias, C, (swz >> 4) * 256, (swz & 15) * 256, C_DIM, H_DIM);
}

// ---------------------------------------------------------------------------
// Ring-4 pipelined 128x128 GEMM (R1 structure) — fc2. + XCD m-major swizzle.
// ---------------------------------------------------------------------------
template<int EPI, typename OUT_T>
__global__ __launch_bounds__(256)
void gemm_ring(const unsigned short* __restrict__ A,
               const unsigned short* __restrict__ B,
               const float* __restrict__ bias,
               OUT_T* __restrict__ C, int M, int N, int K)
{
    __shared__ unsigned short As[4][128 * 32];
    __shared__ unsigned short Bs[4][128 * 32];   // 64 KB total

    const int t    = threadIdx.x;
    const int lane = t & 63;
    const int wave = t >> 6;

    // XCD swizzle (requires gridDim.x*gridDim.y % 8 == 0; fc2: 512 blocks,
    // chunk 64/XCD = 4 m-blocks -> A-slice 4 MB ~= L2).
    const int nwgy = gridDim.y;
    const int nwg  = gridDim.x * nwgy;
    const int hwid = blockIdx.x + blockIdx.y * gridDim.x;
    const int swz  = (hwid & 7) * (nwg >> 3) + (hwid >> 3);
    const int m0 = (swz / nwgy) * 128, n0 = (swz % nwgy) * 128;

    const int wm = (wave >> 1) * 64, wn = (wave & 1) * 64;
    const int lr = lane & 15;
    const int kq = lane >> 4;
    const int lrow = lane >> 2;
    const int lcol = (lane & 3) * 8;
    const int NT = K >> 5;

    const int arow = m0 + wave * 32 + lrow;
    const int brow = n0 + wave * 32 + lrow;
    const int rb   = wave * 32;

    f32x4 acc[4][4] = {};

#define STAGE_T(slot, ktile) do {                                              \
    const int koff_ = (ktile) * 32 + lcol;                                     \
    G2L16(&A[(size_t)(arow)      * K + koff_], &As[slot][ rb       * 32]);     \
    G2L16(&A[(size_t)(arow + 16) * K + koff_], &As[slot][(rb + 16) * 32]);     \
    G2L16(&B[(size_t)(brow)      * K + koff_], &Bs[slot][ rb       * 32]);     \
    G2L16(&B[(size_t)(brow + 16) * K + koff_], &Bs[slot][(rb + 16) * 32]);     \
  } while (0)

    STAGE_T(0, 0);
    STAGE_T(1, 1);
    STAGE_T(2, 2);

    for (int kt = 0; kt < NT; ++kt) {
        if (kt < NT - 2)       asm volatile("s_waitcnt vmcnt(8)" ::: "memory");
        else if (kt == NT - 2) asm volatile("s_waitcnt vmcnt(4)" ::: "memory");
        else                   asm volatile("s_waitcnt vmcnt(0)" ::: "memory");
        __builtin_amdgcn_s_barrier();

        const int s = kt & 3;
        short8 af[4], bfr[4];
        #pragma unroll
        for (int i = 0; i < 4; ++i)
            af[i] = *(const short8*)&As[s][(wm + i * 16 + lr) * 32 + kq * 8];
        #pragma unroll
        for (int j = 0; j < 4; ++j)
            bfr[j] = *(const short8*)&Bs[s][(wn + j * 16 + lr) * 32 + kq * 8];
        #pragma unroll
        for (int i = 0; i < 4; ++i)
            #pragma unroll
            for (int j = 0; j < 4; ++j)
                acc[i][j] = __builtin_amdgcn_mfma_f32_16x16x32_bf16(af[i], bfr[j], acc[i][j], 0, 0, 0);

        if (kt + 3 < NT) STAGE_T((kt + 3) & 3, kt + 3);
    }

    #pragma unroll
    for (int j = 0; j < 4; ++j) {
        const int col = n0 + wn + j * 16 + lr;
        float bv = 0.f;
        if (EPI > 0) bv = bias[col];
        #pragma unroll
        for (int i = 0; i < 4; ++i) {
            #pragma unroll
            for (int r = 0; r < 4; ++r) {
                const int row = m0 + wm + i * 16 + kq * 4 + r;
                float v = acc[i][j][r] + bv;
                if (EPI == 1) v = fmaxf(v, 0.f);
                if constexpr (sizeof(OUT_T) == 2) C[(size_t)row * N + col] = f2bf(v);
                else                              C[(size_t)row * N + col] = v;
            }
        }
    }
#undef STAGE_T
}

// ---------------------------------------------------------------------------
// MFMA flash attention (no max-shift softmax; deferred sum reduction).
// Original verified version (V staged+transposed in LDS). Untouched.
// ---------------------------------------------------------------------------
#define LDK 72
__global__ __launch_bounds__(256)
void attn_mfma(const unsigned short* __restrict__ Qg,
               const unsigned short* __restrict__ Kg,
               const unsigned short* __restrict__ Vg,
               unsigned short* __restrict__ Og)
{
    __shared__ unsigned short Ks[64 * LDK];
    __shared__ unsigned short Vt[64 * LDK];
    __shared__ unsigned short Ps[64 * LDK];

    const int t    = threadIdx.x;
    const int lane = t & 63;
    const int wave = t >> 6;
    const int lr   = lane & 15;
    const int quad = lane >> 4;
    const int bh = blockIdx.y;
    const int b  = bh >> 5, h = bh & 31;
    const int q0 = blockIdx.x * 64;
    const int colbase = h * 64;

    short8 qf[2];
    {
        const size_t qrow = (size_t)(b * NSEQ + q0 + wave * 16 + lr) * C_DIM + colbase;
        #pragma unroll
        for (int kc = 0; kc < 2; ++kc) {
            short8 raw = *(const short8*)(Qg + qrow + kc * 32 + quad * 8);
            short8 sc;
            #pragma unroll
            for (int j = 0; j < 8; ++j)
                sc[j] = (short)f2bf(bf2f((unsigned short)raw[j]) * 0.125f);
            qf[kc] = sc;
        }
    }

    f32x4 Oacc[4] = {};
    float li[4] = {};

    for (int kt = 0; kt < 16; ++kt) {
        __syncthreads();
        {
            const int r = t >> 2, sg = (t & 3) * 16;
            const size_t grow = (size_t)(b * NSEQ + kt * 64 + r) * C_DIM + colbase + sg;
            *(int4*)&Ks[r * LDK + sg]     = *(const int4*)(Kg + grow);
            *(int4*)&Ks[r * LDK + sg + 8] = *(const int4*)(Kg + grow + 8);
        }
        {
            const int key = t & 63, d0 = (t >> 6) * 16;
            const size_t grow = (size_t)(b * NSEQ + kt * 64 + key) * C_DIM + colbase + d0;
            int4 u0 = *(const int4*)(Vg + grow);
            int4 u1 = *(const int4*)(Vg + grow + 8);
            const unsigned short* us0 = (const unsigned short*)&u0;
            const unsigned short* us1 = (const unsigned short*)&u1;
            #pragma unroll
            for (int j = 0; j < 8; ++j) {
                Vt[(d0 + j)     * LDK + key] = us0[j];
                Vt[(d0 + j + 8) * LDK + key] = us1[j];
            }
        }
        __syncthreads();

        f32x4 s[4] = {};
        #pragma unroll
        for (int n = 0; n < 4; ++n)
            #pragma unroll
            for (int kc = 0; kc < 2; ++kc) {
                short8 kf = *(const short8*)&Ks[(n * 16 + lr) * LDK + kc * 32 + quad * 8];
                s[n] = __builtin_amdgcn_mfma_f32_16x16x32_bf16(qf[kc], kf, s[n], 0, 0, 0);
            }

        float p[4][4];
        #pragma unroll
        for (int r = 0; r < 4; ++r) {
            #pragma unroll
            for (int n = 0; n < 4; ++n) { p[n][r] = __expf(s[n][r]); }
            li[r] += p[0][r] + p[1][r] + p[2][r] + p[3][r];
        }

        #pragma unroll
        for (int r = 0; r < 4; ++r)
            #pragma unroll
            for (int n = 0; n < 4; ++n)
                Ps[(wave * 16 + quad * 4 + r) * LDK + n * 16 + lr] = f2bf(p[n][r]);

        short8 pf[2];
        #pragma unroll
        for (int kc = 0; kc < 2; ++kc)
            pf[kc] = *(const short8*)&Ps[(wave * 16 + lr) * LDK + kc * 32 + quad * 8];

        #pragma unroll
        for (int n = 0; n < 4; ++n)
            #pragma unroll
            for (int kc = 0; kc < 2; ++kc) {
                short8 vf = *(const short8*)&Vt[(n * 16 + lr) * LDK + kc * 32 + quad * 8];
                Oacc[n] = __builtin_amdgcn_mfma_f32_16x16x32_bf16(pf[kc], vf, Oacc[n], 0, 0, 0);
            }
    }

    #pragma unroll
    for (int r = 0; r < 4; ++r) {
        #pragma unroll
        for (int off = 1; off < 16; off <<= 1) li[r] += __shfl_xor(li[r], off, 64);
        const float inv = 1.f / li[r];
        const size_t rowb = (size_t)(b * NSEQ + q0 + wave * 16 + quad * 4 + r) * C_DIM + colbase;
        #pragma unroll
        for (int n = 0; n < 4; ++n)
            Og[rowb + n * 16 + lr] = f2bf(Oacc[n][r] * inv);
    }
}

// ---------------------------------------------------------------------------
// LN1: y = LN(attn_bf16 + x_f32) * w + b -> y16 (bf16)
// ---------------------------------------------------------------------------
__global__ __launch_bounds__(256)
void ln_fused1(const unsigned short* __restrict__ a, const float* __restrict__ xr,
               const float* __restrict__ w, const float* __restrict__ bb,
               unsigned short* __restrict__ y16)
{
    const int row = blockIdx.x, t = threadIdx.x;
    const size_t base = (size_t)row * C_DIM;
    const int c0 = t * 8;
    float v[8];
    int4 ai = *(const int4*)(a + base + c0);
    const unsigned short* as = (const unsigned short*)&ai;
    float4 x0 = *(const float4*)(xr + base + c0);
    float4 x1 = *(const float4*)(xr + base + c0 + 4);
    v[0] = bf2f(as[0]) + x0.x; v[1] = bf2f(as[1]) + x0.y;
    v[2] = bf2f(as[2]) + x0.z; v[3] = bf2f(as[3]) + x0.w;
    v[4] = bf2f(as[4]) + x1.x; v[5] = bf2f(as[5]) + x1.y;
    v[6] = bf2f(as[6]) + x1.z; v[7] = bf2f(as[7]) + x1.w;

    float s = 0.f, s2 = 0.f;
    #pragma unroll
    for (int k = 0; k < 8; ++k) { s += v[k]; s2 += v[k] * v[k]; }
    #pragma unroll
    for (int off = 32; off; off >>= 1) { s += __shfl_xor(s, off, 64); s2 += __shfl_xor(s2, off, 64); }
    __shared__ float red[8];
    if ((t & 63) == 0) { red[t >> 6] = s; red[4 + (t >> 6)] = s2; }
    __syncthreads();
    s  = red[0] + red[1] + red[2] + red[3];
    s2 = red[4] + red[5] + red[6] + red[7];
    const float mu = s * (1.f / C_DIM);
    const float rs = rsqrtf(s2 * (1.f / C_DIM) - mu * mu + 1e-6f);

    float4 w0 = *(const float4*)(w + c0);
    float4 w1 = *(const float4*)(w + c0 + 4);
    float4 b0 = *(const float4*)(bb + c0);
    float4 b1 = *(const float4*)(bb + c0 + 4);
    const float* wf = (const float*)&w0; const float* wg = (const float*)&w1;
    const float* bf = (const float*)&b0; const float* bg = (const float*)&b1;
    unsigned short o16[8];
    #pragma unroll
    for (int k = 0; k < 4; ++k) {
        o16[k]     = f2bf((v[k]     - mu) * rs * wf[k] + bf[k]);
        o16[k + 4] = f2bf((v[k + 4] - mu) * rs * wg[k] + bg[k]);
    }
    *(int4*)(y16 + base + c0) = *(const int4*)o16;
}

// ---------------------------------------------------------------------------
// LN2: out = LN(y16 + h2) * w + b -> fp32 d_out. y16,h2 bf16; w,b fp32.
// ---------------------------------------------------------------------------
__global__ __launch_bounds__(256)
void ln_fused2(const unsigned short* __restrict__ a, const unsigned short* __restrict__ b2,
               const float* __restrict__ w, const float* __restrict__ bb,
               float* __restrict__ out)
{
    const int row = blockIdx.x, t = threadIdx.x;
    const size_t base = (size_t)row * C_DIM;
    const int c0 = t * 8;
    float v[8];
    int4 ai = *(const int4*)(a + base + c0);
    int4 bi = *(const int4*)(b2 + base + c0);
    const unsigned short* as = (const unsigned short*)&ai;
    const unsigned short* bs = (const unsigned short*)&bi;
    #pragma unroll
    for (int k = 0; k < 8; ++k) v[k] = bf2f(as[k]) + bf2f(bs[k]);

    float s = 0.f, s2 = 0.f;
    #pragma unroll
    for (int k = 0; k < 8; ++k) { s += v[k]; s2 += v[k] * v[k]; }
    #pragma unroll
    for (int off = 32; off; off >>= 1) { s += __shfl_xor(s, off, 64); s2 += __shfl_xor(s2, off, 64); }
    __shared__ float red[8];
    if ((t & 63) == 0) { red[t >> 6] = s; red[4 + (t >> 6)] = s2; }
    __syncthreads();
    s  = red[0] + red[1] + red[2] + red[3];
    s2 = red[4] + red[5] + red[6] + red[7];
    const float mu = s * (1.f / C_DIM);
    const float rs = rsqrtf(s2 * (1.f / C_DIM) - mu * mu + 1e-6f);

    float4 w0 = *(const float4*)(w + c0);
    float4 w1 = *(const float4*)(w + c0 + 4);
    float4 b0 = *(const float4*)(bb + c0);
    float4 b1 = *(const float4*)(bb + c0 + 4);
    const float* wf = (const float*)&w0; const float* wg = (const float*)&w1;
    const float* bf = (const float*)&b0; const float* bg = (const float*)&b1;
    float4 o0, o1;
    #pragma unroll
    for (int k = 0; k < 4; ++k) {
        ((float*)&o0)[k] = (v[k]     - mu) * rs * wf[k] + bf[k];
        ((float*)&o1)[k] = (v[k + 4] - mu) * rs * wg[k] + bg[k];
    }
    *(float4*)(out + base + c0)     = o0;
    *(float4*)(out + base + c0 + 4) = o1;
}

// ---------------------------------------------------------------------------
extern "C" void kernel_launch(void* const* d_in, const int* in_sizes, int n_in,
                              void* d_out, int out_size, void* d_ws, size_t ws_size,
                              hipStream_t stream)
{
    (void)in_sizes; (void)n_in; (void)out_size; (void)ws_size;
    const float* x    = (const float*)d_in[0];
    const float* wq   = (const float*)d_in[1];
    const float* wk   = (const float*)d_in[2];
    const float* wv   = (const float*)d_in[3];
    const float* ln1w = (const float*)d_in[4];
    const float* ln1b = (const float*)d_in[5];
    const float* fc1w = (const float*)d_in[6];
    const float* fc1b = (const float*)d_in[7];
    const float* fc2w = (const float*)d_in[8];
    const float* fc2b = (const float*)d_in[9];
    const float* ln2w = (const float*)d_in[10];
    const float* ln2b = (const float*)d_in[11];

    char* ws = (char*)d_ws;
    const size_t MB16 = (size_t)BN_ROWS * C_DIM * 2;       // 16.78 MB (bf16 4096x2048)
    unsigned short* xb    = (unsigned short*)(ws);
    unsigned short* attnb = (unsigned short*)(ws);
    unsigned short* wqb   = (unsigned short*)(ws + MB16);
    unsigned short* wkb   = (unsigned short*)(ws + MB16 + MB16 / 2);
    unsigned short* y16   = (unsigned short*)(ws + MB16);
    unsigned short* wvb   = (unsigned short*)(ws + 2 * MB16);
    unsigned short* fc1wb = (unsigned short*)(ws + 2 * MB16 + MB16 / 2);
    unsigned short* fc2wb = (unsigned short*)(ws + 3 * MB16 + MB16 / 2);
    unsigned short* q_ws  = (unsigned short*)(ws + 4 * MB16 + MB16 / 2);
    unsigned short* h2    = (unsigned short*)(ws + 4 * MB16 + MB16 / 2);
    unsigned short* k_ws  = (unsigned short*)(ws + 5 * MB16 + MB16 / 2);
    unsigned short* v_ws  = (unsigned short*)(ws + 6 * MB16 + MB16 / 2);
    unsigned short* hbuf  = (unsigned short*)(ws + 5 * MB16 + MB16 / 2);

    dim3 blk(256);

    // fp32 -> bf16 conversions, one launch (16 elems/thread)
    cvt_all<<<dim3(9216), blk, 0, stream>>>(x, xb, wq, wqb, wk, wkb, wv, wvb,
                                            fc1w, fc1wb, fc2w, fc2wb);

    // Fused QKV (m97 structure + XCD m-major swizzle): grid (32,48)
    gemm_qkv<<<dim3(32, 48), blk, 0, stream>>>(xb, wqb, wkb, wvb, q_ws, k_ws, v_ws);
    // attention (writes attnb over xb — xb dead after QKV)
    attn_mfma<<<dim3(NSEQ / 64, NBATCH * NHEAD), blk, 0, stream>>>(q_ws, k_ws, v_ws, attnb);
    // LN1 (residual with original fp32 x) -> y16 (over wqb/wkb — dead)
    ln_fused1<<<dim3(BN_ROWS), blk, 0, stream>>>(attnb, x, ln1w, ln1b, y16);
    // fc1: 256^2 8-phase + XCD swizzle, grid (16,16)
    gemm256_fc1<<<dim3(16, 16), dim3(512), 0, stream>>>(y16, fc1wb, fc1b, hbuf);
    // fc2: ring-4 128x128 + XCD swizzle, grid (32,16)
    gemm_ring<2, unsigned short><<<dim3(32, 16), blk, 0, stream>>>(hbuf, fc2wb, fc2b, h2, BN_ROWS, C_DIM, H_DIM);
    // LN2 (residual + LN) -> fp32 output
    ln_fused2<<<dim3(BN_ROWS), blk, 0, stream>>>(y16, h2, ln2w, ln2b, (float*)d_out);
}

// Round 7
// 548.679 us; speedup vs baseline: 1.0305x; 1.0305x over previous
//
#include <hip/hip_runtime.h>

// Problem shape (hardcoded from reference setup_inputs):
// B=4, N=1024, C=2048, H=2*C=4096, num_head=32, d_head=64
#define C_DIM   2048
#define H_DIM   4096
#define NSEQ    1024
#define NBATCH  4
#define BN_ROWS 4096    // B*N
#define NHEAD   32
#define DHEAD   64

typedef __attribute__((ext_vector_type(8))) short  short8;
typedef __attribute__((ext_vector_type(4))) float  f32x4;

__device__ __forceinline__ float bf2f(unsigned short u) {
    union { unsigned int i; float f; } v; v.i = ((unsigned int)u) << 16; return v.f;
}
__device__ __forceinline__ unsigned short f2bf(float f) {
    union { float f; unsigned int i; } v; v.f = f;
    unsigned int r = v.i + 0x7fffu + ((v.i >> 16) & 1u);   // round-to-nearest-even
    return (unsigned short)(r >> 16);
}

// async global->LDS, 16B per lane; lds base must be wave-uniform, lane i
// lands at lds + i*16 (measured m97/m104 semantics).
#define G2L16(gp, lp) \
    __builtin_amdgcn_global_load_lds((const __attribute__((address_space(1))) void*)(gp), \
                                     (__attribute__((address_space(3))) void*)(lp), 16, 0, 0)

// ---------------------------------------------------------------------------
// Fused fp32 -> bf16 conversion, 16 elems/thread (4096/block). Boundaries:
//   x:2048 | wq:1024 | wk:1024 | wv:1024 | fc1w:2048 | fc2w:2048 (tot 9216)
// ---------------------------------------------------------------------------
__global__ __launch_bounds__(256)
void cvt_all(const float* __restrict__ x,   unsigned short* __restrict__ xo,
             const float* __restrict__ w0,  unsigned short* __restrict__ w0o,
             const float* __restrict__ w1,  unsigned short* __restrict__ w1o,
             const float* __restrict__ w2,  unsigned short* __restrict__ w2o,
             const float* __restrict__ w3,  unsigned short* __restrict__ w3o,
             const float* __restrict__ w4,  unsigned short* __restrict__ w4o)
{
    int bid = blockIdx.x;
    const float* src; unsigned short* dst;
    if      (bid < 2048) { src = x;  dst = xo;  }
    else if (bid < 3072) { src = w0; dst = w0o; bid -= 2048; }
    else if (bid < 4096) { src = w1; dst = w1o; bid -= 3072; }
    else if (bid < 5120) { src = w2; dst = w2o; bid -= 4096; }
    else if (bid < 7168) { src = w3; dst = w3o; bid -= 5120; }
    else                 { src = w4; dst = w4o; bid -= 7168; }
    const size_t i = ((size_t)bid * 256 + threadIdx.x) * 16;
    #pragma unroll
    for (int h = 0; h < 2; ++h) {
        float4 a = *(const float4*)(src + i + h * 8);
        float4 b = *(const float4*)(src + i + h * 8 + 4);
        unsigned short o[8] = { f2bf(a.x), f2bf(a.y), f2bf(a.z), f2bf(a.w),
                                f2bf(b.x), f2bf(b.y), f2bf(b.z), f2bf(b.w) };
        *(int4*)(dst + i + h * 8) = *(const int4*)o;
    }
}

// ---------------------------------------------------------------------------
// Fused QKV GEMM — m97 2-barrier structure, verified 124.4 us (VGPR 76,
// Occ 30%, MfmaUtil 36%). R5 lesson: XCD swizzle DOUBLED L2-miss traffic
// (default bx-fastest order already shares B-panels) — reverted. R3 lesson:
// don't touch the register budget. grid (32,48); ng selects wq/wk/wv.
// ---------------------------------------------------------------------------
__global__ __launch_bounds__(256)
void gemm_qkv(const unsigned short* __restrict__ A,
              const unsigned short* __restrict__ Wq,
              const unsigned short* __restrict__ Wk,
              const unsigned short* __restrict__ Wv,
              unsigned short* __restrict__ Qo,
              unsigned short* __restrict__ Ko,
              unsigned short* __restrict__ Vo)
{
    __shared__ unsigned short As[128 * 32];
    __shared__ unsigned short Bs[128 * 32];

    const int t    = threadIdx.x;
    const int lane = t & 63;
    const int wave = t >> 6;
    const int m0 = blockIdx.x * 128;
    const int ng = blockIdx.y * 128;           // global n in [0,6144)
    const unsigned short* B; unsigned short* Cp; int n0;
    if      (ng < 2048) { B = Wq; Cp = Qo; n0 = ng; }
    else if (ng < 4096) { B = Wk; Cp = Ko; n0 = ng - 2048; }
    else                { B = Wv; Cp = Vo; n0 = ng - 4096; }

    const int wm = (wave >> 1) * 64, wn = (wave & 1) * 64;
    const int lr = lane & 15;
    const int kq = lane >> 4;

    f32x4 acc[4][4] = {};

    const int lrow = lane >> 2;
    const int lcol = (lane & 3) * 8;

    for (int kt = 0; kt < C_DIM; kt += 32) {
        __syncthreads();
        #pragma unroll
        for (int p = 0; p < 2; ++p) {
            const int rb = wave * 32 + p * 16;
            G2L16(&A[(size_t)(m0 + rb + lrow) * C_DIM + kt + lcol], &As[rb * 32]);
            G2L16(&B[(size_t)(n0 + rb + lrow) * C_DIM + kt + lcol], &Bs[rb * 32]);
        }
        __syncthreads();

        short8 af[4], bf[4];
        #pragma unroll
        for (int i = 0; i < 4; ++i)
            af[i] = *(const short8*)&As[(wm + i * 16 + lr) * 32 + kq * 8];
        #pragma unroll
        for (int j = 0; j < 4; ++j)
            bf[j] = *(const short8*)&Bs[(wn + j * 16 + lr) * 32 + kq * 8];
        #pragma unroll
        for (int i = 0; i < 4; ++i)
            #pragma unroll
            for (int j = 0; j < 4; ++j)
                acc[i][j] = __builtin_amdgcn_mfma_f32_16x16x32_bf16(af[i], bf[j], acc[i][j], 0, 0, 0);
    }

    #pragma unroll
    for (int j = 0; j < 4; ++j) {
        const int col = n0 + wn + j * 16 + lr;
        #pragma unroll
        for (int i = 0; i < 4; ++i) {
            #pragma unroll
            for (int r = 0; r < 4; ++r) {
                const int row = m0 + wm + i * 16 + kq * 4 + r;
                Cp[(size_t)row * C_DIM + col] = f2bf(acc[i][j][r]);
            }
        }
    }
}

// ---------------------------------------------------------------------------
// 256x256 8-phase GEMM (verified R3/R4; 0 bank conflicts) — fc1. No swizzle
// (R5: swizzle hurt locality).
// ---------------------------------------------------------------------------
template<int EPI>
__device__ __forceinline__
void gemm256_body(const unsigned short* __restrict__ A,
                  const unsigned short* __restrict__ B,
                  const float* __restrict__ bias,
                  unsigned short* __restrict__ C,
                  const int m0, const int n0, const int K, const int ldc)
{
    __shared__ unsigned short As[2][256 * 64];
    __shared__ unsigned short Bs[2][256 * 64];

    const int t  = threadIdx.x;
    const int l  = t & 63;
    const int w  = t >> 6;          // 0..7
    const int wr = w >> 2;          // 0..1  (M half)
    const int wc = w & 3;           // 0..3  (N quarter)
    const int lr = l & 15;
    const int kq = l >> 4;
    const int slotA = lr & 7;       // read-side swizzle term

    const int sr = l >> 3;                    // row 0..7 within 8-row group
    const int sg = ((l & 7) ^ sr) * 8;        // swizzled source granule (ushort)

    f32x4 acc[8][4] = {};
    short8 bf[4][2], af[2][2];

#define STG(src, srow0, ktile, ldsdst) do {                                         \
    const unsigned short* gp0_ = (src) + (size_t)((srow0) + w * 8 + sr) * K         \
                                  + (ktile) * 64 + sg;                              \
    const unsigned short* gp1_ = (src) + (size_t)((srow0) + 64 + w * 8 + sr) * K    \
                                  + (ktile) * 64 + sg;                              \
    G2L16(gp0_, (ldsdst) + (w * 8) * 64);                                           \
    G2L16(gp1_, (ldsdst) + (64 + w * 8) * 64);                                      \
  } while (0)

#define LDB(buf) do {                                                               \
    _Pragma("unroll") for (int n_ = 0; n_ < 4; ++n_)                                \
      _Pragma("unroll") for (int ks_ = 0; ks_ < 2; ++ks_)                           \
        bf[n_][ks_] = *(const short8*)&Bs[buf][                                     \
            (wc * 64 + n_ * 16 + lr) * 64 + (((ks_ << 2) | kq) ^ slotA) * 8];       \
  } while (0)

#define LDA(buf, q) do {                                                            \
    _Pragma("unroll") for (int i_ = 0; i_ < 2; ++i_)                                \
      _Pragma("unroll") for (int ks_ = 0; ks_ < 2; ++ks_)                           \
        af[i_][ks_] = *(const short8*)&As[buf][                                     \
            (wr * 128 + ((q) * 2 + i_) * 16 + lr) * 64                              \
            + (((ks_ << 2) | kq) ^ slotA) * 8];                                     \
  } while (0)

#define MM(q) do {                                                                  \
    __builtin_amdgcn_s_setprio(1);                                                  \
    _Pragma("unroll") for (int i_ = 0; i_ < 2; ++i_)                                \
      _Pragma("unroll") for (int n_ = 0; n_ < 4; ++n_)                              \
        _Pragma("unroll") for (int ks_ = 0; ks_ < 2; ++ks_)                         \
          acc[(q) * 2 + i_][n_] = __builtin_amdgcn_mfma_f32_16x16x32_bf16(          \
              af[i_][ks_], bf[n_][ks_], acc[(q) * 2 + i_][n_], 0, 0, 0);            \
    __builtin_amdgcn_s_setprio(0);                                                  \
  } while (0)

#define BARR() __builtin_amdgcn_s_barrier()
#define WLG0() asm volatile("s_waitcnt lgkmcnt(0)" ::: "memory")

    const int NT = K >> 6;      // K-tiles of 64
    const int IT = NT >> 1;     // iterations (2 tiles each)

    STG(B, n0,       0, &Bs[0][0]);
    STG(B, n0 + 128, 0, &Bs[0][128 * 64]);
    STG(A, m0,       0, &As[0][0]);
    STG(A, m0 + 128, 0, &As[0][128 * 64]);
    STG(B, n0,       1, &Bs[1][0]);
    STG(B, n0 + 128, 1, &Bs[1][128 * 64]);
    asm volatile("s_waitcnt vmcnt(4)" ::: "memory");   // T0 landed; T1.B in flight
    BARR();

    for (int it = 0; it < IT; ++it) {
        const int T1 = 2 * it + 1, T2 = 2 * it + 2, T3 = 2 * it + 3;
        const bool haveT2 = (T2 < NT), haveT3 = (T3 < NT);

        LDB(0); LDA(0, 0);
        STG(A, m0, T1, &As[1][0]);
        BARR(); WLG0(); MM(0); BARR();

        LDA(0, 1);
        STG(A, m0 + 128, T1, &As[1][128 * 64]);
        BARR(); WLG0(); MM(1); BARR();

        LDA(0, 2);
        if (haveT2) STG(B, n0, T2, &Bs[0][0]);
        BARR(); WLG0(); MM(2); BARR();

        LDA(0, 3);
        if (haveT2) STG(B, n0 + 128, T2, &Bs[0][128 * 64]);
        BARR(); WLG0(); MM(3);
        if (haveT2) asm volatile("s_waitcnt vmcnt(4)" ::: "memory");
        else        asm volatile("s_waitcnt vmcnt(0)" ::: "memory");
        BARR();

        LDB(1); LDA(1, 0);
        if (haveT2) STG(A, m0, T2, &As[0][0]);
        BARR(); WLG0(); MM(0); BARR();

        LDA(1, 1);
        if (haveT2) STG(A, m0 + 128, T2, &As[0][128 * 64]);
        BARR(); WLG0(); MM(1); BARR();

        LDA(1, 2);
        if (haveT3) STG(B, n0, T3, &Bs[1][0]);
        BARR(); WLG0(); MM(2); BARR();

        LDA(1, 3);
        if (haveT3) STG(B, n0 + 128, T3, &Bs[1][128 * 64]);
        BARR(); WLG0(); MM(3);
        if (it + 1 < IT) asm volatile("s_waitcnt vmcnt(4)" ::: "memory");
        BARR();
    }

    #pragma unroll
    for (int n = 0; n < 4; ++n) {
        const int col = n0 + wc * 64 + n * 16 + lr;
        float bv = 0.f;
        if (EPI > 0) bv = bias[col];
        #pragma unroll
        for (int m = 0; m < 8; ++m) {
            #pragma unroll
            for (int r = 0; r < 4; ++r) {
                const int row = m0 + wr * 128 + m * 16 + kq * 4 + r;
                float v = acc[m][n][r] + bv;
                if (EPI == 1) v = fmaxf(v, 0.f);
                C[(size_t)row * ldc + col] = f2bf(v);
            }
        }
    }
#undef STG
#undef LDB
#undef LDA
#undef MM
#undef BARR
#undef WLG0
}

__global__ __launch_bounds__(512, 2)
void gemm256_fc1(const unsigned short* __restrict__ A,
                 const unsigned short* __restrict__ B,
                 const float* __restrict__ bias,
                 unsigned short* __restrict__ C)
{
    gemm256_body<1>(A, B, bias, C, blockIdx.x * 256, blockIdx.y * 256, C_DIM, H_DIM);
}

// ---------------------------------------------------------------------------
// Ring-4 pipelined 128x128 GEMM (R1 structure, verified R2) — fc2. No swizzle.
// ---------------------------------------------------------------------------
template<int EPI, typename OUT_T>
__global__ __launch_bounds__(256)
void gemm_ring(const unsigned short* __restrict__ A,
               const unsigned short* __restrict__ B,
               const float* __restrict__ bias,
               OUT_T* __restrict__ C, int M, int N, int K)
{
    __shared__ unsigned short As[4][128 * 32];
    __shared__ unsigned short Bs[4][128 * 32];   // 64 KB total

    const int t    = threadIdx.x;
    const int lane = t & 63;
    const int wave = t >> 6;
    const int m0 = blockIdx.x * 128, n0 = blockIdx.y * 128;
    const int wm = (wave >> 1) * 64, wn = (wave & 1) * 64;
    const int lr = lane & 15;
    const int kq = lane >> 4;
    const int lrow = lane >> 2;
    const int lcol = (lane & 3) * 8;
    const int NT = K >> 5;

    const int arow = m0 + wave * 32 + lrow;
    const int brow = n0 + wave * 32 + lrow;
    const int rb   = wave * 32;

    f32x4 acc[4][4] = {};

#define STAGE_T(slot, ktile) do {                                              \
    const int koff_ = (ktile) * 32 + lcol;                                     \
    G2L16(&A[(size_t)(arow)      * K + koff_], &As[slot][ rb       * 32]);     \
    G2L16(&A[(size_t)(arow + 16) * K + koff_], &As[slot][(rb + 16) * 32]);     \
    G2L16(&B[(size_t)(brow)      * K + koff_], &Bs[slot][ rb       * 32]);     \
    G2L16(&B[(size_t)(brow + 16) * K + koff_], &Bs[slot][(rb + 16) * 32]);     \
  } while (0)

    STAGE_T(0, 0);
    STAGE_T(1, 1);
    STAGE_T(2, 2);

    for (int kt = 0; kt < NT; ++kt) {
        if (kt < NT - 2)       asm volatile("s_waitcnt vmcnt(8)" ::: "memory");
        else if (kt == NT - 2) asm volatile("s_waitcnt vmcnt(4)" ::: "memory");
        else                   asm volatile("s_waitcnt vmcnt(0)" ::: "memory");
        __builtin_amdgcn_s_barrier();

        const int s = kt & 3;
        short8 af[4], bfr[4];
        #pragma unroll
        for (int i = 0; i < 4; ++i)
            af[i] = *(const short8*)&As[s][(wm + i * 16 + lr) * 32 + kq * 8];
        #pragma unroll
        for (int j = 0; j < 4; ++j)
            bfr[j] = *(const short8*)&Bs[s][(wn + j * 16 + lr) * 32 + kq * 8];
        #pragma unroll
        for (int i = 0; i < 4; ++i)
            #pragma unroll
            for (int j = 0; j < 4; ++j)
                acc[i][j] = __builtin_amdgcn_mfma_f32_16x16x32_bf16(af[i], bfr[j], acc[i][j], 0, 0, 0);

        if (kt + 3 < NT) STAGE_T((kt + 3) & 3, kt + 3);
    }

    #pragma unroll
    for (int j = 0; j < 4; ++j) {
        const int col = n0 + wn + j * 16 + lr;
        float bv = 0.f;
        if (EPI > 0) bv = bias[col];
        #pragma unroll
        for (int i = 0; i < 4; ++i) {
            #pragma unroll
            for (int r = 0; r < 4; ++r) {
                const int row = m0 + wm + i * 16 + kq * 4 + r;
                float v = acc[i][j][r] + bv;
                if (EPI == 1) v = fmaxf(v, 0.f);
                if constexpr (sizeof(OUT_T) == 2) C[(size_t)row * N + col] = f2bf(v);
                else                              C[(size_t)row * N + col] = v;
            }
        }
    }
#undef STAGE_T
}

// ---------------------------------------------------------------------------
// MFMA flash attention. NEW: T14 async-STAGE split — the global K/V loads
// for step kt+1 are issued right after step kt's LDS writes, so their L2
// latency hides under the QK^T+softmax+PV compute phase (m214 r277: +17%).
// LDS layout, MFMA structure, softmax unchanged.
// ---------------------------------------------------------------------------
#define LDK 72
__global__ __launch_bounds__(256)
void attn_mfma(const unsigned short* __restrict__ Qg,
               const unsigned short* __restrict__ Kg,
               const unsigned short* __restrict__ Vg,
               unsigned short* __restrict__ Og)
{
    __shared__ unsigned short Ks[64 * LDK];
    __shared__ unsigned short Vt[64 * LDK];
    __shared__ unsigned short Ps[64 * LDK];

    const int t    = threadIdx.x;
    const int lane = t & 63;
    const int wave = t >> 6;
    const int lr   = lane & 15;
    const int quad = lane >> 4;
    const int bh = blockIdx.y;
    const int b  = bh >> 5, h = bh & 31;
    const int q0 = blockIdx.x * 64;
    const int colbase = h * 64;

    short8 qf[2];
    {
        const size_t qrow = (size_t)(b * NSEQ + q0 + wave * 16 + lr) * C_DIM + colbase;
        #pragma unroll
        for (int kc = 0; kc < 2; ++kc) {
            short8 raw = *(const short8*)(Qg + qrow + kc * 32 + quad * 8);
            short8 sc;
            #pragma unroll
            for (int j = 0; j < 8; ++j)
                sc[j] = (short)f2bf(bf2f((unsigned short)raw[j]) * 0.125f);
            qf[kc] = sc;
        }
    }

    // staging lane geometry + prologue loads (kt = 0)
    const int r_k   = t >> 2, sg_k = (t & 3) * 16;
    const int key_v = t & 63, d0_v = (t >> 6) * 16;
    const size_t base_bh = (size_t)(b * NSEQ) * C_DIM + colbase;
    int4 k0, k1, v0, v1;
    {
        const size_t gk = base_bh + (size_t)r_k * C_DIM + sg_k;
        k0 = *(const int4*)(Kg + gk);
        k1 = *(const int4*)(Kg + gk + 8);
        const size_t gv = base_bh + (size_t)key_v * C_DIM + d0_v;
        v0 = *(const int4*)(Vg + gv);
        v1 = *(const int4*)(Vg + gv + 8);
    }

    f32x4 Oacc[4] = {};
    float li[4] = {};

    for (int kt = 0; kt < 16; ++kt) {
        __syncthreads();
        // deposit staged regs -> LDS
        *(int4*)&Ks[r_k * LDK + sg_k]     = k0;
        *(int4*)&Ks[r_k * LDK + sg_k + 8] = k1;
        {
            const unsigned short* us0 = (const unsigned short*)&v0;
            const unsigned short* us1 = (const unsigned short*)&v1;
            #pragma unroll
            for (int j = 0; j < 8; ++j) {
                Vt[(d0_v + j)     * LDK + key_v] = us0[j];
                Vt[(d0_v + j + 8) * LDK + key_v] = us1[j];
            }
        }
        // issue next-step loads; latency hides under this step's compute
        if (kt + 1 < 16) {
            const size_t gk = base_bh + (size_t)((kt + 1) * 64 + r_k) * C_DIM + sg_k;
            k0 = *(const int4*)(Kg + gk);
            k1 = *(const int4*)(Kg + gk + 8);
            const size_t gv = base_bh + (size_t)((kt + 1) * 64 + key_v) * C_DIM + d0_v;
            v0 = *(const int4*)(Vg + gv);
            v1 = *(const int4*)(Vg + gv + 8);
        }
        __syncthreads();

        f32x4 s[4] = {};
        #pragma unroll
        for (int n = 0; n < 4; ++n)
            #pragma unroll
            for (int kc = 0; kc < 2; ++kc) {
                short8 kf = *(const short8*)&Ks[(n * 16 + lr) * LDK + kc * 32 + quad * 8];
                s[n] = __builtin_amdgcn_mfma_f32_16x16x32_bf16(qf[kc], kf, s[n], 0, 0, 0);
            }

        float p[4][4];
        #pragma unroll
        for (int r = 0; r < 4; ++r) {
            #pragma unroll
            for (int n = 0; n < 4; ++n) { p[n][r] = __expf(s[n][r]); }
            li[r] += p[0][r] + p[1][r] + p[2][r] + p[3][r];
        }

        #pragma unroll
        for (int r = 0; r < 4; ++r)
            #pragma unroll
            for (int n = 0; n < 4; ++n)
                Ps[(wave * 16 + quad * 4 + r) * LDK + n * 16 + lr] = f2bf(p[n][r]);

        short8 pf[2];
        #pragma unroll
        for (int kc = 0; kc < 2; ++kc)
            pf[kc] = *(const short8*)&Ps[(wave * 16 + lr) * LDK + kc * 32 + quad * 8];

        #pragma unroll
        for (int n = 0; n < 4; ++n)
            #pragma unroll
            for (int kc = 0; kc < 2; ++kc) {
                short8 vf = *(const short8*)&Vt[(n * 16 + lr) * LDK + kc * 32 + quad * 8];
                Oacc[n] = __builtin_amdgcn_mfma_f32_16x16x32_bf16(pf[kc], vf, Oacc[n], 0, 0, 0);
            }
    }

    #pragma unroll
    for (int r = 0; r < 4; ++r) {
        #pragma unroll
        for (int off = 1; off < 16; off <<= 1) li[r] += __shfl_xor(li[r], off, 64);
        const float inv = 1.f / li[r];
        const size_t rowb = (size_t)(b * NSEQ + q0 + wave * 16 + quad * 4 + r) * C_DIM + colbase;
        #pragma unroll
        for (int n = 0; n < 4; ++n)
            Og[rowb + n * 16 + lr] = f2bf(Oacc[n][r] * inv);
    }
}

// ---------------------------------------------------------------------------
// LN1: y = LN(attn_bf16 + x_f32) * w + b -> y16 (bf16)
// ---------------------------------------------------------------------------
__global__ __launch_bounds__(256)
void ln_fused1(const unsigned short* __restrict__ a, const float* __restrict__ xr,
               const float* __restrict__ w, const float* __restrict__ bb,
               unsigned short* __restrict__ y16)
{
    const int row = blockIdx.x, t = threadIdx.x;
    const size_t base = (size_t)row * C_DIM;
    const int c0 = t * 8;
    float v[8];
    int4 ai = *(const int4*)(a + base + c0);
    const unsigned short* as = (const unsigned short*)&ai;
    float4 x0 = *(const float4*)(xr + base + c0);
    float4 x1 = *(const float4*)(xr + base + c0 + 4);
    v[0] = bf2f(as[0]) + x0.x; v[1] = bf2f(as[1]) + x0.y;
    v[2] = bf2f(as[2]) + x0.z; v[3] = bf2f(as[3]) + x0.w;
    v[4] = bf2f(as[4]) + x1.x; v[5] = bf2f(as[5]) + x1.y;
    v[6] = bf2f(as[6]) + x1.z; v[7] = bf2f(as[7]) + x1.w;

    float s = 0.f, s2 = 0.f;
    #pragma unroll
    for (int k = 0; k < 8; ++k) { s += v[k]; s2 += v[k] * v[k]; }
    #pragma unroll
    for (int off = 32; off; off >>= 1) { s += __shfl_xor(s, off, 64); s2 += __shfl_xor(s2, off, 64); }
    __shared__ float red[8];
    if ((t & 63) == 0) { red[t >> 6] = s; red[4 + (t >> 6)] = s2; }
    __syncthreads();
    s  = red[0] + red[1] + red[2] + red[3];
    s2 = red[4] + red[5] + red[6] + red[7];
    const float mu = s * (1.f / C_DIM);
    const float rs = rsqrtf(s2 * (1.f / C_DIM) - mu * mu + 1e-6f);

    float4 w0 = *(const float4*)(w + c0);
    float4 w1 = *(const float4*)(w + c0 + 4);
    float4 b0 = *(const float4*)(bb + c0);
    float4 b1 = *(const float4*)(bb + c0 + 4);
    const float* wf = (const float*)&w0; const float* wg = (const float*)&w1;
    const float* bf = (const float*)&b0; const float* bg = (const float*)&b1;
    unsigned short o16[8];
    #pragma unroll
    for (int k = 0; k < 4; ++k) {
        o16[k]     = f2bf((v[k]     - mu) * rs * wf[k] + bf[k]);
        o16[k + 4] = f2bf((v[k + 4] - mu) * rs * wg[k] + bg[k]);
    }
    *(int4*)(y16 + base + c0) = *(const int4*)o16;
}

// ---------------------------------------------------------------------------
// LN2: out = LN(y16 + h2) * w + b -> fp32 d_out. y16,h2 bf16; w,b fp32.
// ---------------------------------------------------------------------------
__global__ __launch_bounds__(256)
void ln_fused2(const unsigned short* __restrict__ a, const unsigned short* __restrict__ b2,
               const float* __restrict__ w, const float* __restrict__ bb,
               float* __restrict__ out)
{
    const int row = blockIdx.x, t = threadIdx.x;
    const size_t base = (size_t)row * C_DIM;
    const int c0 = t * 8;
    float v[8];
    int4 ai = *(const int4*)(a + base + c0);
    int4 bi = *(const int4*)(b2 + base + c0);
    const unsigned short* as = (const unsigned short*)&ai;
    const unsigned short* bs = (const unsigned short*)&bi;
    #pragma unroll
    for (int k = 0; k < 8; ++k) v[k] = bf2f(as[k]) + bf2f(bs[k]);

    float s = 0.f, s2 = 0.f;
    #pragma unroll
    for (int k = 0; k < 8; ++k) { s += v[k]; s2 += v[k] * v[k]; }
    #pragma unroll
    for (int off = 32; off; off >>= 1) { s += __shfl_xor(s, off, 64); s2 += __shfl_xor(s2, off, 64); }
    __shared__ float red[8];
    if ((t & 63) == 0) { red[t >> 6] = s; red[4 + (t >> 6)] = s2; }
    __syncthreads();
    s  = red[0] + red[1] + red[2] + red[3];
    s2 = red[4] + red[5] + red[6] + red[7];
    const float mu = s * (1.f / C_DIM);
    const float rs = rsqrtf(s2 * (1.f / C_DIM) - mu * mu + 1e-6f);

    float4 w0 = *(const float4*)(w + c0);
    float4 w1 = *(const float4*)(w + c0 + 4);
    float4 b0 = *(const float4*)(bb + c0);
    float4 b1 = *(const float4*)(bb + c0 + 4);
    const float* wf = (const float*)&w0; const float* wg = (const float*)&w1;
    const float* bf = (const float*)&b0; const float* bg = (const float*)&b1;
    float4 o0, o1;
    #pragma unroll
    for (int k = 0; k < 4; ++k) {
        ((float*)&o0)[k] = (v[k]     - mu) * rs * wf[k] + bf[k];
        ((float*)&o1)[k] = (v[k + 4] - mu) * rs * wg[k] + bg[k];
    }
    *(float4*)(out + base + c0)     = o0;
    *(float4*)(out + base + c0 + 4) = o1;
}

// ---------------------------------------------------------------------------
extern "C" void kernel_launch(void* const* d_in, const int* in_sizes, int n_in,
                              void* d_out, int out_size, void* d_ws, size_t ws_size,
                              hipStream_t stream)
{
    (void)in_sizes; (void)n_in; (void)out_size; (void)ws_size;
    const float* x    = (const float*)d_in[0];
    const float* wq   = (const float*)d_in[1];
    const float* wk   = (const float*)d_in[2];
    const float* wv   = (const float*)d_in[3];
    const float* ln1w = (const float*)d_in[4];
    const float* ln1b = (const float*)d_in[5];
    const float* fc1w = (const float*)d_in[6];
    const float* fc1b = (const float*)d_in[7];
    const float* fc2w = (const float*)d_in[8];
    const float* fc2b = (const float*)d_in[9];
    const float* ln2w = (const float*)d_in[10];
    const float* ln2b = (const float*)d_in[11];

    char* ws = (char*)d_ws;
    const size_t MB16 = (size_t)BN_ROWS * C_DIM * 2;       // 16.78 MB (bf16 4096x2048)
    unsigned short* xb    = (unsigned short*)(ws);
    unsigned short* attnb = (unsigned short*)(ws);
    unsigned short* wqb   = (unsigned short*)(ws + MB16);
    unsigned short* wkb   = (unsigned short*)(ws + MB16 + MB16 / 2);
    unsigned short* y16   = (unsigned short*)(ws + MB16);
    unsigned short* wvb   = (unsigned short*)(ws + 2 * MB16);
    unsigned short* fc1wb = (unsigned short*)(ws + 2 * MB16 + MB16 / 2);
    unsigned short* fc2wb = (unsigned short*)(ws + 3 * MB16 + MB16 / 2);
    unsigned short* q_ws  = (unsigned short*)(ws + 4 * MB16 + MB16 / 2);
    unsigned short* h2    = (unsigned short*)(ws + 4 * MB16 + MB16 / 2);
    unsigned short* k_ws  = (unsigned short*)(ws + 5 * MB16 + MB16 / 2);
    unsigned short* v_ws  = (unsigned short*)(ws + 6 * MB16 + MB16 / 2);
    unsigned short* hbuf  = (unsigned short*)(ws + 5 * MB16 + MB16 / 2);

    dim3 blk(256);

    // fp32 -> bf16 conversions, one launch (16 elems/thread)
    cvt_all<<<dim3(9216), blk, 0, stream>>>(x, xb, wq, wqb, wk, wkb, wv, wvb,
                                            fc1w, fc1wb, fc2w, fc2wb);

    // Fused QKV (m97 structure, default block order): grid (32,48)
    gemm_qkv<<<dim3(32, 48), blk, 0, stream>>>(xb, wqb, wkb, wvb, q_ws, k_ws, v_ws);
    // attention (T14 async-stage; writes attnb over xb — xb dead after QKV)
    attn_mfma<<<dim3(NSEQ / 64, NBATCH * NHEAD), blk, 0, stream>>>(q_ws, k_ws, v_ws, attnb);
    // LN1 (residual with original fp32 x) -> y16 (over wqb/wkb — dead)
    ln_fused1<<<dim3(BN_ROWS), blk, 0, stream>>>(attnb, x, ln1w, ln1b, y16);
    // fc1: 256^2 8-phase (bias+relu), grid (16,16) = 256 blocks = 1 block/CU
    gemm256_fc1<<<dim3(16, 16), dim3(512), 0, stream>>>(y16, fc1wb, fc1b, hbuf);
    // fc2: ring-4 128x128 (bias), grid (32,16)=512 blocks
    gemm_ring<2, unsigned short><<<dim3(32, 16), blk, 0, stream>>>(hbuf, fc2wb, fc2b, h2, BN_ROWS, C_DIM, H_DIM);
    // LN2 (residual + LN) -> fp32 output
    ln_fused2<<<dim3(BN_ROWS), blk, 0, stream>>>(y16, h2, ln2w, ln2b, (float*)d_out);
}